// Round 1
// baseline (334.732 us; speedup 1.0000x reference)
//
#include <hip/hip_runtime.h>

// HierarchicalChronoFormer forward, MI355X (gfx950).
// B=8, S=4096, D=512, H=8, dk=64, BIN=64, NB=64, T_BINS=1000.

typedef __attribute__((ext_vector_type(8))) short bf16x8;
typedef __attribute__((ext_vector_type(4))) float f32x4;

#define DEVI __device__ __forceinline__

DEVI unsigned short f2bf(float f) {
  union { float f; unsigned u; } v; v.f = f;
  unsigned r = v.u + 0x7FFFu + ((v.u >> 16) & 1u);
  return (unsigned short)(r >> 16);
}

// ---------------- weight transpose-pack: Wt[n][k] = bf16(W[k][n]); all mats 512x512
struct TPackArgs { const float* s[8]; unsigned short* d[8]; };

__global__ __launch_bounds__(256) void k_tpack8(TPackArgs args) {
  __shared__ float tile[64][65];
  int mat = blockIdx.x >> 6;
  int tl = blockIdx.x & 63;
  const float* W = args.s[mat];
  unsigned short* Wt = args.d[mat];
  int n0 = (tl & 7) << 6, k0 = (tl >> 3) << 6;
  int t = threadIdx.x, j = t & 63, i0 = t >> 6;
#pragma unroll
  for (int rr = 0; rr < 16; ++rr) {
    int i = rr * 4 + i0;
    tile[i][j] = W[(size_t)(k0 + i) * 512 + n0 + j];
  }
  __syncthreads();
#pragma unroll
  for (int rr = 0; rr < 16; ++rr) {
    int i = rr * 4 + i0;
    Wt[(size_t)(n0 + i) * 512 + k0 + j] = f2bf(tile[j][i]);
  }
}

__global__ __launch_bounds__(256) void k_concat3(const float* __restrict__ a,
    const float* __restrict__ b, const float* __restrict__ c, float* __restrict__ o) {
  int i = blockIdx.x * 256 + threadIdx.x;  // grid 6 -> i < 1536
  float v = (i < 512) ? a[i] : (i < 1024) ? b[i - 512] : c[i - 1024];
  o[i] = v;
}

// ---------------- abs_t = cumsum(max(td,0)) per batch row
__global__ __launch_bounds__(64) void k_cumsum(const float* __restrict__ td, float* __restrict__ abs_t) {
  int b = blockIdx.x, lane = threadIdx.x;
  const float* row = td + (size_t)b * 4096;
  float* out = abs_t + (size_t)b * 4096;
  float carry = 0.f;
  for (int c = 0; c < 64; ++c) {
    float v = fmaxf(row[c * 64 + lane], 0.f);
#pragma unroll
    for (int off = 1; off < 64; off <<= 1) {
      float n = __shfl_up(v, off, 64);
      if (lane >= off) v += n;
    }
    out[c * 64 + lane] = carry + v;
    carry += __shfl(v, 63, 64);
  }
}

// ---------------- bin stats: bin_abs -> bin_rel, bin_mask, last_idx
__global__ __launch_bounds__(64) void k_binstats(const int* __restrict__ x, const float* __restrict__ abs_t,
    float* __restrict__ bin_rel, int* __restrict__ bin_mask, int* __restrict__ last_idx) {
  int b = blockIdx.x, lane = threadIdx.x;
  __shared__ float babs[64];
  __shared__ int bmask[64];
  for (int nb = 0; nb < 64; ++nb) {
    int gt = b * 4096 + nb * 64 + lane;
    int valid = x[gt] != 0;
    float a = valid ? abs_t[gt] : 0.f;
#pragma unroll
    for (int off = 32; off; off >>= 1) a = fmaxf(a, __shfl_xor(a, off, 64));
    unsigned long long bal = __ballot(valid);
    if (lane == 0) { babs[nb] = a; bmask[nb] = (bal != 0ULL) ? 1 : 0; }
  }
  __syncthreads();
  float rel = (lane == 0) ? 0.f : fmaxf(babs[lane] - babs[lane - 1], 0.f);
  bin_rel[b * 64 + lane] = rel;
  bin_mask[b * 64 + lane] = bmask[lane];
  unsigned long long bal = __ballot(bmask[lane] != 0);
  if (lane == 0) last_idx[b] = max(__popcll(bal) - 1, 0);
}

// ---------------- h = ee[x] (0 if x==0) + emb_rel[rb] + emb_abs[ab], bf16 out
__global__ __launch_bounds__(256) void k_embed(const int* __restrict__ x, const float* __restrict__ td,
    const float* __restrict__ abs_t, const float* __restrict__ ee, const float* __restrict__ er,
    const float* __restrict__ ea, unsigned short* __restrict__ h) {
  int t = threadIdx.x;
  int tok = blockIdx.x * 4 + (t >> 6);
  int lane = t & 63;
  int c0 = lane * 8;
  int xi = x[tok];
  int rb = (int)td[tok]; rb = min(max(rb, 0), 999);
  int ab = (int)abs_t[tok]; ab = min(max(ab, 0), 999);
  const f32x4* pr = (const f32x4*)(er + (size_t)rb * 512 + c0);
  const f32x4* pa = (const f32x4*)(ea + (size_t)ab * 512 + c0);
  f32x4 s0 = pr[0] + pa[0];
  f32x4 s1 = pr[1] + pa[1];
  if (xi != 0) {
    const f32x4* pe = (const f32x4*)(ee + (size_t)xi * 512 + c0);
    s0 += pe[0]; s1 += pe[1];
  }
  bf16x8 o;
#pragma unroll
  for (int i = 0; i < 4; ++i) { o[i] = (short)f2bf(s0[i]); o[4 + i] = (short)f2bf(s1[i]); }
  *(bf16x8*)(h + (size_t)tok * 512 + c0) = o;
}

// ---------------- GEMM: C[M,N] = A[M,512](bf16) @ Wt[N,512]^T(bf16) + bias[N]
// 128x128 tile, BK=64, 4 waves (2x2), 16x16x32 MFMA. Reg-staged, +8 padded LDS.
template<int OUT_BF16>
__global__ __launch_bounds__(256) void k_gemm(const unsigned short* __restrict__ A,
    const unsigned short* __restrict__ Wt, const float* __restrict__ bias,
    void* __restrict__ Cout, int N, int tiles_n) {
  __shared__ unsigned short As[128 * 72];
  __shared__ unsigned short Bs[128 * 72];
  int bx = blockIdx.x % tiles_n;
  int by = blockIdx.x / tiles_n;
  int m0 = by << 7, n0 = bx << 7;
  int t = threadIdx.x;
  int lane = t & 63, w = t >> 6;
  int wm = w >> 1, wn = w & 1;
  f32x4 acc[4][4] = {};
  for (int k0 = 0; k0 < 512; k0 += 64) {
    __syncthreads();
#pragma unroll
    for (int i = 0; i < 4; ++i) {
      int idx = t + i * 256;
      int row = idx >> 3, seg = idx & 7;
      *(bf16x8*)&As[row * 72 + seg * 8] = *(const bf16x8*)&A[(size_t)(m0 + row) * 512 + k0 + seg * 8];
      *(bf16x8*)&Bs[row * 72 + seg * 8] = *(const bf16x8*)&Wt[(size_t)(n0 + row) * 512 + k0 + seg * 8];
    }
    __syncthreads();
#pragma unroll
    for (int ks = 0; ks < 2; ++ks) {
      bf16x8 af[4], bb[4];
#pragma unroll
      for (int i = 0; i < 4; ++i) {
        af[i] = *(const bf16x8*)&As[(wm * 64 + i * 16 + (lane & 15)) * 72 + ks * 32 + (lane >> 4) * 8];
        bb[i] = *(const bf16x8*)&Bs[(wn * 64 + i * 16 + (lane & 15)) * 72 + ks * 32 + (lane >> 4) * 8];
      }
#pragma unroll
      for (int i = 0; i < 4; ++i)
#pragma unroll
        for (int j = 0; j < 4; ++j)
          acc[i][j] = __builtin_amdgcn_mfma_f32_16x16x32_bf16(af[i], bb[j], acc[i][j], 0, 0, 0);
    }
  }
#pragma unroll
  for (int i = 0; i < 4; ++i) {
    int rowb = m0 + wm * 64 + i * 16 + ((lane >> 4) << 2);
#pragma unroll
    for (int j = 0; j < 4; ++j) {
      int col = n0 + wn * 64 + j * 16 + (lane & 15);
      float bv = bias[col];
#pragma unroll
      for (int r = 0; r < 4; ++r) {
        float v = acc[i][j][r] + bv;
        if (OUT_BF16) ((unsigned short*)Cout)[(size_t)(rowb + r) * N + col] = f2bf(v);
        else ((float*)Cout)[(size_t)(rowb + r) * N + col] = v;
      }
    }
  }
}

// ---------------- fused attention over one 64-token block; wave w = head w.
// qkv row layout [1536]: q at col h*64, k at 512+h*64, v at 1024+h*64.
__global__ __launch_bounds__(512) void k_attn(const unsigned short* __restrict__ qkv,
    const float* __restrict__ td, const int* __restrict__ validv,
    const float* __restrict__ temb, unsigned short* __restrict__ ctx) {
  __shared__ float bias_s[8][64];
  __shared__ int valid_s[64];
  __shared__ unsigned short P_s[8][64][72];
  __shared__ unsigned short Vt_s[8][64][72];
  int blk = blockIdx.x;
  int t = threadIdx.x, h = t >> 6, lane = t & 63;
  size_t base = (size_t)blk * 64;
  if (t < 64) {
    valid_s[t] = (validv[base + t] != 0) ? 1 : 0;
    int tb = (int)td[base + t];
    tb = min(max(tb, 0), 999);
#pragma unroll
    for (int hh = 0; hh < 8; ++hh) bias_s[hh][t] = temb[tb * 8 + hh];
  }
  {  // stage V transposed: Vt[feat][key]; lane = key
    const unsigned short* vp = qkv + (base + lane) * 1536 + 1024 + h * 64;
#pragma unroll
    for (int f8 = 0; f8 < 8; ++f8) {
      bf16x8 v8 = *(const bf16x8*)(vp + f8 * 8);
#pragma unroll
      for (int j = 0; j < 8; ++j) Vt_s[h][f8 * 8 + j][lane] = (unsigned short)v8[j];
    }
  }
  __syncthreads();
  bf16x8 qa[2][4], kb[2][4];
#pragma unroll
  for (int ks = 0; ks < 2; ++ks)
#pragma unroll
    for (int i = 0; i < 4; ++i) {
      int row = i * 16 + (lane & 15);
      int kk = ks * 32 + (lane >> 4) * 8;
      qa[ks][i] = *(const bf16x8*)&qkv[(base + row) * 1536 + h * 64 + kk];
      kb[ks][i] = *(const bf16x8*)&qkv[(base + row) * 1536 + 512 + h * 64 + kk];
    }
  f32x4 acc[4][4] = {};
#pragma unroll
  for (int ks = 0; ks < 2; ++ks)
#pragma unroll
    for (int i = 0; i < 4; ++i)
#pragma unroll
      for (int j = 0; j < 4; ++j)
        acc[i][j] = __builtin_amdgcn_mfma_f32_16x16x32_bf16(qa[ks][i], kb[ks][j], acc[i][j], 0, 0, 0);
  // masked+biased softmax over keys; row r held by 16-lane group, 4 frag-cols
#pragma unroll
  for (int i = 0; i < 4; ++i) {
#pragma unroll
    for (int r = 0; r < 4; ++r) {
      float sv[4];
#pragma unroll
      for (int j = 0; j < 4; ++j) {
        int key = j * 16 + (lane & 15);
        float s = acc[i][j][r] * 0.125f;
        sv[j] = valid_s[key] ? (s + bias_s[h][key]) : -1e9f;
      }
      float m = fmaxf(fmaxf(sv[0], sv[1]), fmaxf(sv[2], sv[3]));
#pragma unroll
      for (int off = 1; off < 16; off <<= 1) m = fmaxf(m, __shfl_xor(m, off, 64));
      float p[4], sum = 0.f;
#pragma unroll
      for (int j = 0; j < 4; ++j) { p[j] = __expf(sv[j] - m); sum += p[j]; }
#pragma unroll
      for (int off = 1; off < 16; off <<= 1) sum += __shfl_xor(sum, off, 64);
      float inv = 1.f / sum;
      int row = i * 16 + ((lane >> 4) << 2) + r;
#pragma unroll
      for (int j = 0; j < 4; ++j) P_s[h][row][j * 16 + (lane & 15)] = f2bf(p[j] * inv);
    }
  }
  __syncthreads();
  f32x4 acc2[4][4] = {};
#pragma unroll
  for (int ks = 0; ks < 2; ++ks) {
    bf16x8 pa[4], vb[4];
    int kk = ks * 32 + (lane >> 4) * 8;
#pragma unroll
    for (int i = 0; i < 4; ++i) {
      pa[i] = *(const bf16x8*)&P_s[h][i * 16 + (lane & 15)][kk];
      vb[i] = *(const bf16x8*)&Vt_s[h][i * 16 + (lane & 15)][kk];
    }
#pragma unroll
    for (int i = 0; i < 4; ++i)
#pragma unroll
      for (int j = 0; j < 4; ++j)
        acc2[i][j] = __builtin_amdgcn_mfma_f32_16x16x32_bf16(pa[i], vb[j], acc2[i][j], 0, 0, 0);
  }
#pragma unroll
  for (int i = 0; i < 4; ++i) {
    int rowb = i * 16 + ((lane >> 4) << 2);
#pragma unroll
    for (int j = 0; j < 4; ++j) {
      int col = h * 64 + j * 16 + (lane & 15);
#pragma unroll
      for (int r = 0; r < 4; ++r)
        ctx[(base + rowb + r) * 512 + col] = f2bf(acc2[i][j][r]);
    }
  }
}

// ---------------- LayerNorm rows of X[*,512]; POOL=1: masked mean-pool 64 rows -> bf16[512]
template<int POOL>
__global__ __launch_bounds__(256) void k_lnpool(const float* __restrict__ X,
    const float* __restrict__ g, const float* __restrict__ bt,
    const int* __restrict__ validv, void* __restrict__ out) {
  __shared__ float pool_s[4][512];
  __shared__ int cnt_s[4];
  int blk = blockIdx.x;
  int t = threadIdx.x, w = t >> 6, lane = t & 63;
  float gv[8], bv[8];
#pragma unroll
  for (int i = 0; i < 8; ++i) { gv[i] = g[lane * 8 + i]; bv[i] = bt[lane * 8 + i]; }
  float psum[8] = {0.f, 0.f, 0.f, 0.f, 0.f, 0.f, 0.f, 0.f};
  int cnt = 0;
  for (int r0 = 0; r0 < 16; ++r0) {
    int row = blk * 64 + w * 16 + r0;
    const f32x4* xp = (const f32x4*)(X + (size_t)row * 512 + lane * 8);
    f32x4 xa = xp[0], xb = xp[1];
    float s = xa[0] + xa[1] + xa[2] + xa[3] + xb[0] + xb[1] + xb[2] + xb[3];
#pragma unroll
    for (int off = 1; off < 64; off <<= 1) s += __shfl_xor(s, off, 64);
    float mean = s * (1.f / 512.f);
    float vsum = 0.f;
#pragma unroll
    for (int i = 0; i < 4; ++i) { float d0 = xa[i] - mean, d1 = xb[i] - mean; vsum += d0 * d0 + d1 * d1; }
#pragma unroll
    for (int off = 1; off < 64; off <<= 1) vsum += __shfl_xor(vsum, off, 64);
    float rstd = rsqrtf(vsum * (1.f / 512.f) + 1e-5f);
    if (POOL) {
      if (validv[row] != 0) {
        cnt++;
#pragma unroll
        for (int i = 0; i < 4; ++i) {
          psum[i]     += (xa[i] - mean) * rstd * gv[i]     + bv[i];
          psum[4 + i] += (xb[i] - mean) * rstd * gv[4 + i] + bv[4 + i];
        }
      }
    } else {
      f32x4 y0, y1;
#pragma unroll
      for (int i = 0; i < 4; ++i) {
        y0[i] = (xa[i] - mean) * rstd * gv[i]     + bv[i];
        y1[i] = (xb[i] - mean) * rstd * gv[4 + i] + bv[4 + i];
      }
      float* op = (float*)out + (size_t)row * 512 + lane * 8;
      *(f32x4*)op = y0; *(f32x4*)(op + 4) = y1;
    }
  }
  if (POOL) {
#pragma unroll
    for (int i = 0; i < 8; ++i) pool_s[w][lane * 8 + i] = psum[i];
    if (lane == 0) cnt_s[w] = cnt;
    __syncthreads();
    int total = cnt_s[0] + cnt_s[1] + cnt_s[2] + cnt_s[3];
    float denom = fmaxf((float)total, 1.f);
    for (int c = t; c < 512; c += 256) {
      float v = (pool_s[0][c] + pool_s[1][c] + pool_s[2][c] + pool_s[3][c]) / denom;
      ((unsigned short*)out)[(size_t)blk * 512 + c] = f2bf(v);
    }
  }
}

// ---------------- final: pick last row, MLP, sigmoid. grid 8 (one block per batch).
__global__ __launch_bounds__(256) void k_final(const float* __restrict__ h_inter,
    const int* __restrict__ last_idx, const float* __restrict__ w1, const float* __restrict__ b1,
    const float* __restrict__ w2, const float* __restrict__ b2, float* __restrict__ outp) {
  __shared__ float row_s[512];
  __shared__ float red_s[4];
  int b = blockIdx.x, t = threadIdx.x;
  const float* rp = h_inter + (size_t)(b * 64 + last_idx[b]) * 512;
  row_s[t] = rp[t];
  row_s[t + 256] = rp[t + 256];
  __syncthreads();
  float acc = b1[t];
  for (int k = 0; k < 512; ++k) acc += row_s[k] * w1[(size_t)k * 256 + t];
  float hv = fmaxf(acc, 0.f) * w2[t];
#pragma unroll
  for (int off = 1; off < 64; off <<= 1) hv += __shfl_xor(hv, off, 64);
  if ((t & 63) == 0) red_s[t >> 6] = hv;
  __syncthreads();
  if (t == 0) {
    float o = red_s[0] + red_s[1] + red_s[2] + red_s[3] + b2[0];
    outp[b] = 1.f / (1.f + __expf(-o));
  }
}

extern "C" void kernel_launch(void* const* d_in, const int* in_sizes, int n_in,
                              void* d_out, int out_size, void* d_ws, size_t ws_size,
                              hipStream_t stream) {
  const int*   x    = (const int*)d_in[0];
  const float* td   = (const float*)d_in[1];
  const float* ee   = (const float*)d_in[2];
  const float* er   = (const float*)d_in[3];
  const float* ea   = (const float*)d_in[4];
  const float* iq_w = (const float*)d_in[5];  const float* iq_b = (const float*)d_in[6];
  const float* ik_w = (const float*)d_in[7];  const float* ik_b = (const float*)d_in[8];
  const float* iv_w = (const float*)d_in[9];  const float* iv_b = (const float*)d_in[10];
  const float* io_w = (const float*)d_in[11]; const float* io_b = (const float*)d_in[12];
  const float* eq_w = (const float*)d_in[13]; const float* eq_b = (const float*)d_in[14];
  const float* ek_w = (const float*)d_in[15]; const float* ek_b = (const float*)d_in[16];
  const float* ev_w = (const float*)d_in[17]; const float* ev_b = (const float*)d_in[18];
  const float* eo_w = (const float*)d_in[19]; const float* eo_b = (const float*)d_in[20];
  const float* i_temb = (const float*)d_in[21];
  const float* e_temb = (const float*)d_in[22];
  const float* i_g  = (const float*)d_in[23]; const float* i_bt = (const float*)d_in[24];
  const float* e_g  = (const float*)d_in[25]; const float* e_bt = (const float*)d_in[26];
  const float* w1   = (const float*)d_in[27]; const float* b1   = (const float*)d_in[28];
  const float* w2   = (const float*)d_in[29]; const float* b2   = (const float*)d_in[30];

  char* ws = (char*)d_ws;
  size_t off = 0;
  auto alloc = [&](size_t nb) { size_t r = off; off += (nb + 255) & ~(size_t)255; return r; };
  float* abs_t    = (float*)(ws + alloc((size_t)32768 * 4));
  float* bin_rel  = (float*)(ws + alloc(512 * 4));
  int*   bin_mask = (int*)(ws + alloc(512 * 4));
  int*   last_idx = (int*)(ws + alloc(64));
  unsigned short* wqkv_i = (unsigned short*)(ws + alloc((size_t)1536 * 512 * 2));
  unsigned short* wo_i   = (unsigned short*)(ws + alloc((size_t)512 * 512 * 2));
  unsigned short* wqkv_e = (unsigned short*)(ws + alloc((size_t)1536 * 512 * 2));
  unsigned short* wo_e   = (unsigned short*)(ws + alloc((size_t)512 * 512 * 2));
  float* bqkv_i = (float*)(ws + alloc(1536 * 4));
  float* bqkv_e = (float*)(ws + alloc(1536 * 4));
  unsigned short* hbuf = (unsigned short*)(ws + alloc((size_t)32768 * 512 * 2));   // h, then ctx
  char* big = ws + alloc((size_t)32768 * 1536 * 2);                                // qkv bf16, then proj f32
  unsigned short* qkvbuf = (unsigned short*)big;
  float* projbuf = (float*)big;
  unsigned short* bin_repr = (unsigned short*)(ws + alloc((size_t)512 * 512 * 2));
  char* small = ws + alloc((size_t)512 * 1536 * 2);                                // qkv2 bf16, then proj2 f32
  unsigned short* qkv2 = (unsigned short*)small;
  float* proj2 = (float*)small;
  unsigned short* ctx2 = (unsigned short*)(ws + alloc((size_t)512 * 512 * 2));
  float* h_inter = (float*)(ws + alloc((size_t)512 * 512 * 4));

  // 1. pack weights (bf16, transposed) + concat qkv biases
  TPackArgs tp;
  tp.s[0] = iq_w; tp.d[0] = wqkv_i;
  tp.s[1] = ik_w; tp.d[1] = wqkv_i + (size_t)512 * 512;
  tp.s[2] = iv_w; tp.d[2] = wqkv_i + (size_t)1024 * 512;
  tp.s[3] = io_w; tp.d[3] = wo_i;
  tp.s[4] = eq_w; tp.d[4] = wqkv_e;
  tp.s[5] = ek_w; tp.d[5] = wqkv_e + (size_t)512 * 512;
  tp.s[6] = ev_w; tp.d[6] = wqkv_e + (size_t)1024 * 512;
  tp.s[7] = eo_w; tp.d[7] = wo_e;
  k_tpack8<<<512, 256, 0, stream>>>(tp);
  k_concat3<<<6, 256, 0, stream>>>(iq_b, ik_b, iv_b, bqkv_i);
  k_concat3<<<6, 256, 0, stream>>>(eq_b, ek_b, ev_b, bqkv_e);

  // 2. time features
  k_cumsum<<<8, 64, 0, stream>>>(td, abs_t);
  k_binstats<<<8, 64, 0, stream>>>(x, abs_t, bin_rel, bin_mask, last_idx);

  // 3. embeddings -> h (bf16)
  k_embed<<<8192, 256, 0, stream>>>(x, td, abs_t, ee, er, ea, hbuf);

  // 4. intra path
  k_gemm<1><<<256 * 12, 256, 0, stream>>>(hbuf, wqkv_i, bqkv_i, qkvbuf, 1536, 12);
  k_attn<<<512, 512, 0, stream>>>(qkvbuf, td, x, i_temb, hbuf);                    // ctx -> hbuf
  k_gemm<0><<<256 * 4, 256, 0, stream>>>(hbuf, wo_i, io_b, projbuf, 512, 4);       // proj over qkv region
  k_lnpool<1><<<512, 256, 0, stream>>>(projbuf, i_g, i_bt, x, bin_repr);

  // 5. inter path
  k_gemm<1><<<4 * 12, 256, 0, stream>>>(bin_repr, wqkv_e, bqkv_e, qkv2, 1536, 12);
  k_attn<<<8, 512, 0, stream>>>(qkv2, bin_rel, bin_mask, e_temb, ctx2);
  k_gemm<0><<<4 * 4, 256, 0, stream>>>(ctx2, wo_e, eo_b, proj2, 512, 4);           // proj2 over qkv2 region
  k_lnpool<0><<<8, 256, 0, stream>>>(proj2, e_g, e_bt, nullptr, h_inter);

  // 6. head
  k_final<<<8, 256, 0, stream>>>(h_inter, last_idx, w1, b1, w2, b2, (float*)d_out);
}